// Round 1
// baseline (451.660 us; speedup 1.0000x reference)
//
#include <hip/hip_runtime.h>
#include <hip/hip_bf16.h>

// Problem constants
#define B_DIM 64
#define S_DIM 128
#define D1    256
#define D2    256
#define KTOT  65536   // D1*D2
#define NOUT  1024

#define KSPLIT 64
#define KCHUNK (KTOT / KSPLIT)   // 1024 -> 32 MFMA k-steps per block

typedef __attribute__((ext_vector_type(8))) short bf16x8;
typedef __attribute__((ext_vector_type(4))) float f32x4;

// Pack two fp32 -> two bf16 (round-half-up on magnitude; ~2.5 VALU ops/elem)
__device__ inline unsigned pack2bf16(float lo, float hi) {
    unsigned ulo = __float_as_uint(lo);
    unsigned uhi = __float_as_uint(hi);
    ulo = (ulo + 0x8000u) >> 16;
    uhi = (uhi + 0x8000u) & 0xffff0000u;
    return ulo | uhi;
}

// ---------------------------------------------------------------------------
// out[b,o] = bias[o]  (d_out re-poisoned before every launch; atomics add onto this)
__global__ __launch_bounds__(256) void bias_kernel(const float* __restrict__ bias,
                                                   float* __restrict__ out) {
    int i = blockIdx.x * 256 + threadIdx.x;   // grid covers 64*1024
    out[i] = bias[i & (NOUT - 1)];
}

// ---------------------------------------------------------------------------
// tp[b, d*256+e] = sum_s ftab[fillers[b,s], d] * rtab[roles[b,s], e]  (stored bf16)
// Block = (b, 32-wide d-tile). 256 thr = 4 d-subtiles x 64 e-groups (4 e each).
__global__ __launch_bounds__(256) void tp_kernel(const int* __restrict__ fillers,
                                                 const int* __restrict__ roles,
                                                 const float* __restrict__ ftab,
                                                 const float* __restrict__ rtab,
                                                 unsigned short* __restrict__ tp) {
    const int b     = blockIdx.x;        // 0..63
    const int dbase = blockIdx.y * 32;   // 8 tiles of 32
    __shared__ float f_sh[S_DIM][32];
    __shared__ int   ridx[S_DIM];
    const int t = threadIdx.x;

    const int* fb = fillers + b * S_DIM;
    for (int i = t; i < S_DIM * 32; i += 256) {
        int s = i >> 5, dl = i & 31;
        f_sh[s][dl] = ftab[(long)fb[s] * D1 + dbase + dl];
    }
    if (t < S_DIM) ridx[t] = roles[b * S_DIM + t];
    __syncthreads();

    const int dsub = t >> 6;   // 0..3 -> d = dbase + dsub*8 + dl
    const int et   = t & 63;   // e = et*4
    float acc[8][4];
#pragma unroll
    for (int i = 0; i < 8; ++i)
#pragma unroll
        for (int j = 0; j < 4; ++j) acc[i][j] = 0.f;

    for (int s = 0; s < S_DIM; ++s) {
        const float4 rv = *(const float4*)(rtab + ridx[s] * D2 + et * 4);
        const float4 f0 = *(const float4*)&f_sh[s][dsub * 8];
        const float4 f1 = *(const float4*)&f_sh[s][dsub * 8 + 4];
        float fv[8] = {f0.x, f0.y, f0.z, f0.w, f1.x, f1.y, f1.z, f1.w};
        float rr[4] = {rv.x, rv.y, rv.z, rv.w};
#pragma unroll
        for (int dl = 0; dl < 8; ++dl)
#pragma unroll
            for (int c = 0; c < 4; ++c) acc[dl][c] += fv[dl] * rr[c];
    }

    unsigned short* dst = tp + (size_t)b * KTOT + (size_t)(dbase + dsub * 8) * D2 + et * 4;
#pragma unroll
    for (int dl = 0; dl < 8; ++dl) {
        uint2 pp;
        pp.x = pack2bf16(acc[dl][0], acc[dl][1]);
        pp.y = pack2bf16(acc[dl][2], acc[dl][3]);
        *(uint2*)(dst + (size_t)dl * D2) = pp;
    }
}

// ---------------------------------------------------------------------------
// out[64,1024] += tp[64,65536](bf16) @ W[1024,65536]^T, via 16x16x32 bf16 MFMA.
// Grid: (16 n-tiles of 64) x (64 k-splits). Block: 4 waves, each wave owns 16
// cols x all 64 rows. LDS-free: A-frags from tp (16B loads), B-frags = 8
// consecutive fp32 of a W row per lane, converted in-register to bf16.
__global__ __launch_bounds__(256) void gemm_kernel(const unsigned short* __restrict__ tp,
                                                   const float* __restrict__ W,
                                                   float* __restrict__ out) {
    const int nt  = blockIdx.x;            // 0..15
    const int ks  = blockIdx.y;            // 0..KSPLIT-1
    const int w   = threadIdx.x >> 6;      // wave 0..3
    const int L   = threadIdx.x & 63;
    const int l16 = L & 15;
    const int lq  = L >> 4;                // 0..3 (k-quad)
    const int ncol = nt * 64 + w * 16;
    const int k0   = ks * KCHUNK + lq * 8;

    // A: lane holds A[m = l16][k = lq*8 + j]  (m-tile offset added per mfma)
    const unsigned short* tpp = tp + (size_t)l16 * KTOT + k0;
    // B: lane holds B[k = lq*8 + j][n = l16] = W[ncol + l16][k...]
    const float* wp = W + (size_t)(ncol + l16) * KTOT + k0;

    f32x4 acc[4];
#pragma unroll
    for (int mt = 0; mt < 4; ++mt) acc[mt] = (f32x4){0.f, 0.f, 0.f, 0.f};

#pragma unroll 4
    for (int kk = 0; kk < KCHUNK / 32; ++kk) {
        bf16x8 a0 = *(const bf16x8*)(tpp);
        bf16x8 a1 = *(const bf16x8*)(tpp + 16 * KTOT);
        bf16x8 a2 = *(const bf16x8*)(tpp + 32 * KTOT);
        bf16x8 a3 = *(const bf16x8*)(tpp + 48 * KTOT);
        float4 w0 = *(const float4*)wp;
        float4 w1 = *(const float4*)(wp + 4);
        int4 pb;
        pb.x = (int)pack2bf16(w0.x, w0.y);
        pb.y = (int)pack2bf16(w0.z, w0.w);
        pb.z = (int)pack2bf16(w1.x, w1.y);
        pb.w = (int)pack2bf16(w1.z, w1.w);
        bf16x8 bw = *(bf16x8*)&pb;
        acc[0] = __builtin_amdgcn_mfma_f32_16x16x32_bf16(a0, bw, acc[0], 0, 0, 0);
        acc[1] = __builtin_amdgcn_mfma_f32_16x16x32_bf16(a1, bw, acc[1], 0, 0, 0);
        acc[2] = __builtin_amdgcn_mfma_f32_16x16x32_bf16(a2, bw, acc[2], 0, 0, 0);
        acc[3] = __builtin_amdgcn_mfma_f32_16x16x32_bf16(a3, bw, acc[3], 0, 0, 0);
        tpp += 32;
        wp  += 32;
    }

    // D: row = mt*16 + lq*4 + r, col = ncol + l16. Split-K -> atomic accumulate.
#pragma unroll
    for (int mt = 0; mt < 4; ++mt)
#pragma unroll
        for (int r = 0; r < 4; ++r) {
            int row = mt * 16 + lq * 4 + r;
            atomicAdd(out + (size_t)row * NOUT + ncol + l16, acc[mt][r]);
        }
}

// ---------------------------------------------------------------------------
extern "C" void kernel_launch(void* const* d_in, const int* in_sizes, int n_in,
                              void* d_out, int out_size, void* d_ws, size_t ws_size,
                              hipStream_t stream) {
    const int*   fillers = (const int*)d_in[0];
    const int*   roles   = (const int*)d_in[1];
    const float* ftab    = (const float*)d_in[2];
    const float* rtab    = (const float*)d_in[3];
    const float* W       = (const float*)d_in[4];
    const float* bias    = (const float*)d_in[5];
    float* out = (float*)d_out;
    unsigned short* tp = (unsigned short*)d_ws;   // 64*65536 bf16 = 8 MB

    hipLaunchKernelGGL(bias_kernel, dim3(out_size / 256), dim3(256), 0, stream, bias, out);
    hipLaunchKernelGGL(tp_kernel, dim3(B_DIM, 8), dim3(256), 0, stream,
                       fillers, roles, ftab, rtab, tp);
    hipLaunchKernelGGL(gemm_kernel, dim3(16, KSPLIT), dim3(256), 0, stream, tp, W, out);
}